// Round 1
// 327.646 us; speedup vs baseline: 1.0100x; 1.0100x over previous
//
#include <hip/hip_runtime.h>
#include <math.h>

#define BB 32
#define HH 128
#define SS 8192

typedef __attribute__((ext_vector_type(8))) short bf8;
typedef __attribute__((ext_vector_type(4))) float f4;

static __device__ __forceinline__ unsigned short f2bf(float x) {
  union { float f; unsigned int u; } c; c.f = x;
  unsigned int r = c.u + 0x7FFFu + ((c.u >> 16) & 1u);  // RNE
  return (unsigned short)(r >> 16);
}

// ---------------- prep: bias[b][h] = W[h, 256:384] . dec[b]; Abf = bf16(W[:,0:256]) ----------------
__global__ __launch_bounds__(256) void prep_kernel(
    const float* __restrict__ W, const float* __restrict__ dec,
    unsigned short* __restrict__ Abf, float* __restrict__ bias) {
  const int b = blockIdx.x;
  const int tid = threadIdx.x;
  if (tid < HH) {
    const float* wr = W + (size_t)tid * 384 + 256;
    const float* db = dec + (size_t)b * HH;
    float acc = 0.f;
    #pragma unroll 8
    for (int j = 0; j < HH; ++j) acc += wr[j] * db[j];
    bias[b * HH + tid] = acc;
  }
  if (b == 0) {
    for (int idx = tid; idx < HH * 256; idx += 256) {
      int h = idx >> 8, k = idx & 255;
      Abf[idx] = f2bf(W[h * 384 + k]);
    }
  }
}

// ---------------- main: scores[b][s] = sum_h v[h] * tanh(A@X + bias) ----------------
// Streaming-GEMM restructure. Block = 1024 threads (16 waves) = one (b, 256-s strip).
// X streamed in 4 k-chunks of 64: each thread loads 4x float4 (4 consecutive s at 4
// consecutive k-rows; 256B contiguous segments -> full HBM coalescing), converts to
// bf16, transposes in-register (pack 4 k per s) and ds_write_b64 into a double-
// buffered [s][k] LDS tile with XOR chunk swizzle; B-fragments are then contiguous
// conflict-free ds_read_b128 along k. A (128x256 bf16, 64KB) in LDS as before.
// LDS = 64KB A + 2x32KB X = 128KB dynamic -> 1 block/CU, 16 waves (4/SIMD).
// One barrier per chunk; chunk c+1 loads issued before chunk c's MFMAs so HBM
// streams continuously; LDS+MFMA (~2250cy/chunk/CU) hides under the 6400cy stream.
__global__ __launch_bounds__(1024, 4) void attn_main(
    const float* __restrict__ sta, const float* __restrict__ dyn,
    const unsigned short* __restrict__ Abf, const float* __restrict__ bias,
    const float* __restrict__ v, float* __restrict__ scores) {
  extern __shared__ __align__(16) unsigned short smem[];
  unsigned short* LA = smem;            // [128][256] bf16, 16B-chunk swizzled (64KB)
  unsigned short* LX = smem + 32768;    // 2 x [256 s][64 k] bf16, swizzled (2x32KB)

  const int tid  = threadIdx.x;
  const int l    = tid & 63;
  const int w    = tid >> 6;            // wave 0..15
  const int quad = l >> 4;
  const int n16  = l & 15;
  const int b     = blockIdx.x >> 5;
  const int s_blk = (blockIdx.x & 31) << 8;

  // staging thread mapping: this thread covers k_local kq..kq+3, s_local sl..sl+3
  const int kq = ((w >> 2) << 4) + (quad << 2);   // 0..60 step 4
  const int sl = ((w & 3) << 6) + (n16 << 2);     // 0..252 step 4
  const size_t gxoff = ((size_t)b * HH) * SS + s_blk + sl;

  f4 g[4];
  auto issueX = [&](int c) {
    const float* p = (c < 2 ? sta : dyn) + gxoff + (size_t)(((c & 1) << 6) + kq) * SS;
    #pragma unroll
    for (int j = 0; j < 4; ++j) g[j] = *(const f4*)(p + (size_t)j * SS);
  };
  auto convWrite = [&](int buf) {
    unsigned short* X = LX + (buf << 14);
    #pragma unroll
    for (int i = 0; i < 4; ++i) {
      const int srow = sl + i;
      ushort4 o;
      o.x = f2bf(g[0][i]); o.y = f2bf(g[1][i]);
      o.z = f2bf(g[2][i]); o.w = f2bf(g[3][i]);
      // [s][k]: row = 64 shorts (128B, 8 chunks of 16B); phys chunk = (k>>3) ^ (s&7)
      *(ushort4*)&X[(srow << 6) + ((((kq >> 3) ^ (srow & 7)) << 3) | (kq & 7))] = o;
    }
  };

  // ---- prologue: issue X chunk 0, stage A, write X chunk 0 ----
  issueX(0);
  #pragma unroll
  for (int j = 0; j < 4; ++j) {          // A: 64KB, 16B chunks, phys ck = ck ^ (m&7)
    int gc = (j << 10) + tid;            // 0..4095 chunk id; m = gc>>5, ck = gc&31
    int m = gc >> 5, ck = gc & 31;
    bf8 val = *(const bf8*)(Abf + ((size_t)gc << 3));
    *(bf8*)&LA[(m << 8) + ((ck ^ (m & 7)) << 3)] = val;
  }
  convWrite(0);
  __syncthreads();

  f4 acc[8];
  #pragma unroll
  for (int mt = 0; mt < 8; ++mt) acc[mt] = (f4){0.f, 0.f, 0.f, 0.f};

  const int srow = (w << 4) + n16;       // this wave's B-fragment s row
  const int xrow = srow << 6;
  const int sswz = srow & 7;
  const int aswz = n16 & 7;

  #pragma unroll
  for (int c = 0; c < 4; ++c) {
    if (c < 3) issueX(c + 1);            // HBM stream for next chunk in flight
    const unsigned short* X = LX + ((c & 1) << 14);
    bf8 bf0 = *(const bf8*)&X[xrow + ((quad ^ sswz) << 3)];         // ks=0: k=quad*8
    bf8 bf1 = *(const bf8*)&X[xrow + (((4 + quad) ^ sswz) << 3)];   // ks=1: k=32+quad*8
    #pragma unroll
    for (int mt = 0; mt < 8; ++mt) {
      const int arow = (mt << 4) + n16;
      bf8 a0 = *(const bf8*)&LA[(arow << 8) + ((((c << 3) + quad) ^ aswz) << 3)];
      acc[mt] = __builtin_amdgcn_mfma_f32_16x16x32_bf16(a0, bf0, acc[mt], 0, 0, 0);
      bf8 a1 = *(const bf8*)&LA[(arow << 8) + ((((c << 3) + 4 + quad) ^ aswz) << 3)];
      acc[mt] = __builtin_amdgcn_mfma_f32_16x16x32_bf16(a1, bf1, acc[mt], 0, 0, 0);
    }
    if (c < 3) convWrite((c + 1) & 1);   // vmcnt wait + LDS write for next chunk
    __syncthreads();
  }

  // epilogue: z = acc + bias[h]; part += v[h]*tanh(z); reduce over h across quads
  float part = 0.f;
  #pragma unroll
  for (int mt = 0; mt < 8; ++mt) {
    #pragma unroll
    for (int r = 0; r < 4; ++r) {
      const int h = (mt << 4) + (quad << 2) + r;   // C/D row = quad*4 + reg
      part += v[h] * tanhf(acc[mt][r] + bias[(b << 7) + h]);
    }
  }
  part += __shfl_xor(part, 16, 64);
  part += __shfl_xor(part, 32, 64);
  if (quad == 0)
    scores[((size_t)b << 13) + s_blk + srow] = part;
}

// ---------------- softmax over s, in-place on d_out ----------------
__global__ __launch_bounds__(1024) void softmax_kernel(float* __restrict__ out) {
  const int b = blockIdx.x;
  const int tid = threadIdx.x;
  float* row = out + ((size_t)b << 13);
  float4 x0 = ((const float4*)row)[tid];
  float4 x1 = ((const float4*)row)[tid + 1024];
  float lmax = fmaxf(fmaxf(fmaxf(x0.x, x0.y), fmaxf(x0.z, x0.w)),
                     fmaxf(fmaxf(x1.x, x1.y), fmaxf(x1.z, x1.w)));
  __shared__ float red[17];
  #pragma unroll
  for (int o = 32; o >= 1; o >>= 1) lmax = fmaxf(lmax, __shfl_xor(lmax, o, 64));
  if ((tid & 63) == 0) red[tid >> 6] = lmax;
  __syncthreads();
  if (tid < 64) {
    float m = (tid < 16) ? red[tid] : -3.0e38f;
    #pragma unroll
    for (int o = 8; o >= 1; o >>= 1) m = fmaxf(m, __shfl_xor(m, o, 64));
    if (tid == 0) red[16] = m;
  }
  __syncthreads();
  const float gmax = red[16];
  float e[8];
  e[0] = expf(x0.x - gmax); e[1] = expf(x0.y - gmax);
  e[2] = expf(x0.z - gmax); e[3] = expf(x0.w - gmax);
  e[4] = expf(x1.x - gmax); e[5] = expf(x1.y - gmax);
  e[6] = expf(x1.z - gmax); e[7] = expf(x1.w - gmax);
  float ls = e[0] + e[1] + e[2] + e[3] + e[4] + e[5] + e[6] + e[7];
  #pragma unroll
  for (int o = 32; o >= 1; o >>= 1) ls += __shfl_xor(ls, o, 64);
  __syncthreads();   // gmax consumed; safe to reuse red
  if ((tid & 63) == 0) red[tid >> 6] = ls;
  __syncthreads();
  if (tid < 64) {
    float m = (tid < 16) ? red[tid] : 0.f;
    #pragma unroll
    for (int o = 8; o >= 1; o >>= 1) m += __shfl_xor(m, o, 64);
    if (tid == 0) red[16] = m;
  }
  __syncthreads();
  const float inv = 1.0f / red[16];
  float4 o0 = make_float4(e[0] * inv, e[1] * inv, e[2] * inv, e[3] * inv);
  float4 o1 = make_float4(e[4] * inv, e[5] * inv, e[6] * inv, e[7] * inv);
  ((float4*)row)[tid] = o0;
  ((float4*)row)[tid + 1024] = o1;
}

extern "C" void kernel_launch(void* const* d_in, const int* in_sizes, int n_in,
                              void* d_out, int out_size, void* d_ws, size_t ws_size,
                              hipStream_t stream) {
  const float* sta = (const float*)d_in[0];   // (32,128,8192)
  const float* dyn = (const float*)d_in[1];   // (32,128,8192)
  const float* dec = (const float*)d_in[2];   // (32,128)
  const float* v   = (const float*)d_in[3];   // (128)
  const float* W   = (const float*)d_in[4];   // (128,384)

  unsigned short* Abf = (unsigned short*)d_ws;             // 64 KB
  float* bias = (float*)((char*)d_ws + 128 * 256 * 2);     // 16 KB
  float* scores = (float*)d_out;                           // 1 MB, softmaxed in place

  static bool attr_done = false;
  if (!attr_done) {
    (void)hipFuncSetAttribute((const void*)attn_main,
                              hipFuncAttributeMaxDynamicSharedMemorySize, 131072);
    attr_done = true;
  }

  prep_kernel<<<BB, 256, 0, stream>>>(W, dec, Abf, bias);
  attn_main<<<BB * 32, 1024, 131072, stream>>>(sta, dyn, Abf, bias, v, scores);
  softmax_kernel<<<BB, 1024, 0, stream>>>(scores);
}